// Round 5
// baseline (137.473 us; speedup 1.0000x reference)
//
#include <hip/hip_runtime.h>
#include <math.h>

#define SIZE 1024
#define BATCH 32
#define SEQ 2048
#define PARTS 16
#define EPART (SIZE / PARTS)

#define K1_BLOCKS 512          // 16 parts * 32 b * 256 d4 / 256 threads
#define K2_BLOCKS 8192         // 32768 (sp,b) wave-items / 4 waves per block

// Agent-scope relaxed store: compiles to a global_store with device-scope
// cache bits (write-through to the coherent point), so OTHER XCDs can read it
// without the writer doing an L2 writeback fence. Round 3's 25x regression is
// attributed to per-block __threadfence (L2 wb/inv storm); this avoids it.
__device__ __forceinline__ void store_agent_u64(unsigned long long* p,
                                                unsigned long long v) {
    __hip_atomic_store(p, v, __ATOMIC_RELAXED, __HIP_MEMORY_SCOPE_AGENT);
}

// ---------------------------------------------------------------------------
// K1: vpart[part][b][d] = sum_{e in part} dh[b,e]*W[e,d]  (512 blocks), then
// the last 32 ticketed blocks reduce vpart over parts into v[b][d].
// Visibility: vpart written with agent-scope stores; ticket is a RELAXED
// atomic after s_waitcnt vmcnt(0); finishers do ONE acquire fence (32 blocks).
// Deterministic: row r's reduction is identical regardless of which block
// holds ticket r. Spinners <= 32 << co-resident capacity -> no deadlock.
// ---------------------------------------------------------------------------
__global__ __launch_bounds__(256) void k_proj_v(const float* __restrict__ dh,
                                                const float* __restrict__ W,
                                                float* __restrict__ vpart,
                                                float* __restrict__ v,
                                                int* __restrict__ counter) {
    int tid  = blockIdx.x * 256 + threadIdx.x;      // 0 .. 131071
    int part = tid >> 13;                            // 0..15
    int rem  = tid & 8191;
    int b    = rem >> 8;                             // 0..31
    int d4   = rem & 255;                            // 0..255

    const float4* W4  = (const float4*)W;            // [SIZE][SIZE/4]
    const float*  dhb = dh + b * SIZE;
    int e0 = part * EPART;

    float4 acc = make_float4(0.f, 0.f, 0.f, 0.f);
    #pragma unroll 8
    for (int e = e0; e < e0 + EPART; ++e) {
        float  s = dhb[e];                           // wave-uniform scalar
        float4 w = W4[e * (SIZE / 4) + d4];
        acc.x += s * w.x;
        acc.y += s * w.y;
        acc.z += s * w.z;
        acc.w += s * w.w;
    }
    union { float4 f; unsigned long long u[2]; } cv;
    cv.f = acc;
    unsigned long long* dst = (unsigned long long*)
        (((float4*)vpart) + (part * BATCH + b) * (SIZE / 4) + d4);
    store_agent_u64(dst + 0, cv.u[0]);
    store_agent_u64(dst + 1, cv.u[1]);

    asm volatile("s_waitcnt vmcnt(0)" ::: "memory"); // stores at coherent point
    __syncthreads();
    __shared__ int t_s;
    if (threadIdx.x == 0)
        t_s = __hip_atomic_fetch_add(counter, 1, __ATOMIC_RELAXED,
                                     __HIP_MEMORY_SCOPE_AGENT);
    __syncthreads();

    if (t_s >= K1_BLOCKS - 32) {
        if (threadIdx.x == 0) {
            while (__hip_atomic_load(counter, __ATOMIC_RELAXED,
                                     __HIP_MEMORY_SCOPE_AGENT) < K1_BLOCKS)
                __builtin_amdgcn_s_sleep(2);
        }
        __syncthreads();
        __builtin_amdgcn_fence(__ATOMIC_ACQUIRE, "agent");  // inv caches, once

        int r = t_s - (K1_BLOCKS - 32);               // 0..31
        int i = r * 256 + threadIdx.x;                // 0..8191 float4 index
        const float4* vp = (const float4*)vpart;
        float4 a = vp[i];
        #pragma unroll
        for (int p = 1; p < PARTS; ++p) {
            float4 t = vp[p * BATCH * (SIZE / 4) + i];
            a.x += t.x; a.y += t.y; a.z += t.z; a.w += t.w;
        }
        ((float4*)v)[i] = a;                          // flushed at kernel end
    }
}

// ---------------------------------------------------------------------------
// K2: energies[b][s] = v[b] . enc[s][b][:]  -- EXACT round-2 body (2 s-rows
// per wave, plain cached float4 loads; best measured config, 56us total).
// Then the last 32 ticketed blocks each run softmax for one batch row.
// Bias term is constant over s and cancels under softmax shift invariance.
// ---------------------------------------------------------------------------
__global__ __launch_bounds__(256) void k_energy_softmax(const float* __restrict__ enc,
                                                        const float* __restrict__ v,
                                                        float* __restrict__ energies,
                                                        float* __restrict__ out,
                                                        int* __restrict__ counter) {
    int wave = blockIdx.x * 4 + (threadIdx.x >> 6);  // 0..32767
    int lane = threadIdx.x & 63;
    int b  = wave & 31;                              // 0..31
    int sp = wave >> 5;                              // 0..1023 (s-pair)
    size_t s0 = (size_t)sp * 2;

    const float4* row0 = (const float4*)(enc + (s0 * BATCH + b) * SIZE);
    const float4* row1 = (const float4*)(enc + ((s0 + 1) * BATCH + b) * SIZE);
    const float4* vb   = (const float4*)(v + b * SIZE);

    float a0 = 0.f, a1 = 0.f;
    #pragma unroll
    for (int k = 0; k < 4; ++k) {
        int idx = lane + (k << 6);
        float4 e0 = row0[idx];
        float4 e1 = row1[idx];
        float4 vv = vb[idx];
        a0 += e0.x * vv.x + e0.y * vv.y + e0.z * vv.z + e0.w * vv.w;
        a1 += e1.x * vv.x + e1.y * vv.y + e1.z * vv.z + e1.w * vv.w;
    }
    #pragma unroll
    for (int off = 32; off; off >>= 1) {
        a0 += __shfl_down(a0, off, 64);
        a1 += __shfl_down(a1, off, 64);
    }
    if (lane == 0) {
        union { float2 f; unsigned long long u; } cv;
        cv.f = make_float2(a0, a1);
        store_agent_u64((unsigned long long*)(energies + b * SEQ) + sp, cv.u);
    }

    asm volatile("s_waitcnt vmcnt(0)" ::: "memory");
    __syncthreads();
    __shared__ int t_s;
    if (threadIdx.x == 0)
        t_s = __hip_atomic_fetch_add(counter, 1, __ATOMIC_RELAXED,
                                     __HIP_MEMORY_SCOPE_AGENT);
    __syncthreads();

    if (t_s >= K2_BLOCKS - 32) {
        if (threadIdx.x == 0) {
            while (__hip_atomic_load(counter, __ATOMIC_RELAXED,
                                     __HIP_MEMORY_SCOPE_AGENT) < K2_BLOCKS)
                __builtin_amdgcn_s_sleep(2);
        }
        __syncthreads();
        __builtin_amdgcn_fence(__ATOMIC_ACQUIRE, "agent");  // inv caches, once

        int brow = t_s - (K2_BLOCKS - 32);            // 0..31
        const float* row = energies + brow * SEQ;
        int t = threadIdx.x;
        int wid = t >> 6, ln = t & 63;

        float vals[8];
        float m = -INFINITY;
        #pragma unroll
        for (int i = 0; i < 8; ++i) {
            vals[i] = row[t + (i << 8)];
            m = fmaxf(m, vals[i]);
        }
        __shared__ float redm[4];
        #pragma unroll
        for (int off = 32; off; off >>= 1) m = fmaxf(m, __shfl_down(m, off, 64));
        if (ln == 0) redm[wid] = m;
        __syncthreads();
        m = fmaxf(fmaxf(redm[0], redm[1]), fmaxf(redm[2], redm[3]));

        float sum = 0.f;
        #pragma unroll
        for (int i = 0; i < 8; ++i) {
            vals[i] = __expf(vals[i] - m);
            sum += vals[i];
        }
        __shared__ float reds[4];
        #pragma unroll
        for (int off = 32; off; off >>= 1) sum += __shfl_down(sum, off, 64);
        if (ln == 0) reds[wid] = sum;
        __syncthreads();
        sum = reds[0] + reds[1] + reds[2] + reds[3];

        float inv = 1.f / sum;
        #pragma unroll
        for (int i = 0; i < 8; ++i)
            out[brow * SEQ + t + (i << 8)] = vals[i] * inv;
    }
}

// ---------------------------------------------------------------------------
extern "C" void kernel_launch(void* const* d_in, const int* in_sizes, int n_in,
                              void* d_out, int out_size, void* d_ws, size_t ws_size,
                              hipStream_t stream) {
    const float* dh  = (const float*)d_in[0];   // [32, 1024]
    const float* enc = (const float*)d_in[1];   // [2048, 32, 1024]
    const float* W   = (const float*)d_in[2];   // [1024, 1024]
    // d_in[3] = bias: unused (cancels under softmax shift invariance)

    float* ws       = (float*)d_ws;
    float* vpart    = ws;                                   // 16*32*1024 = 524288 f
    float* v        = vpart + PARTS * BATCH * SIZE;         // 32*1024    =  32768 f
    float* energies = v + BATCH * SIZE;                     // 32*2048    =  65536 f
    int*   counters = (int*)(energies + BATCH * SEQ);       // 2 ints

    hipMemsetAsync(counters, 0, 2 * sizeof(int), stream);

    k_proj_v<<<K1_BLOCKS, 256, 0, stream>>>(dh, W, vpart, v, counters + 0);
    k_energy_softmax<<<K2_BLOCKS, 256, 0, stream>>>(enc, v, energies,
                                                    (float*)d_out, counters + 1);
}

// Round 6
// 55.301 us; speedup vs baseline: 2.4859x; 2.4859x over previous
//
#include <hip/hip_runtime.h>
#include <math.h>

#define SIZE 1024
#define BATCH 32
#define SEQ 2048
#define PARTS 16         // e-dim split within a block
#define EPART (SIZE / PARTS)

// ---------------------------------------------------------------------------
// Kernel 1 (fused project+reduce): v[b][d] = sum_e dh[b,e] * W[e,d]
// One block per (b, 64-column chunk): 32*16 = 512 blocks x 256 threads.
// Thread (p, d4l) partial-sums e in [p*64, p*64+64) for column d4 = chunk*16+d4l,
// then an LDS tree reduces over the 16 parts. No cross-block traffic, no vpart.
// W loads: 16 consecutive float4 per p-group -> 256B segments, L2/L3 friendly.
// ---------------------------------------------------------------------------
__global__ __launch_bounds__(256) void k_project(const float* __restrict__ dh,
                                                 const float* __restrict__ W,
                                                 float* __restrict__ v) {
    int bid    = blockIdx.x;        // 0..511
    int b      = bid >> 4;          // 0..31
    int dchunk = bid & 15;          // 0..15
    int tid    = threadIdx.x;
    int p      = tid >> 4;          // 0..15 (e-part)
    int d4l    = tid & 15;          // 0..15
    int d4     = dchunk * 16 + d4l; // 0..255 (float4 column)

    const float4* W4  = (const float4*)W;          // [SIZE][SIZE/4]
    const float*  dhb = dh + b * SIZE;

    float4 acc = make_float4(0.f, 0.f, 0.f, 0.f);
    int e0 = p * EPART;
    #pragma unroll 8
    for (int e = e0; e < e0 + EPART; ++e) {
        float  s = dhb[e];                         // 16-lane broadcast load
        float4 w = W4[e * (SIZE / 4) + d4];
        acc.x += s * w.x;
        acc.y += s * w.y;
        acc.z += s * w.z;
        acc.w += s * w.w;
    }

    __shared__ float4 red[256];                    // [p][d4l], 4KB
    red[tid] = acc;
    __syncthreads();
    #pragma unroll
    for (int stride = 128; stride >= 16; stride >>= 1) {
        if (tid < stride) {
            float4 o = red[tid + stride];
            float4 a = red[tid];
            a.x += o.x; a.y += o.y; a.z += o.z; a.w += o.w;
            red[tid] = a;
        }
        __syncthreads();
    }
    if (tid < 16)
        ((float4*)v)[b * (SIZE / 4) + dchunk * 16 + tid] = red[tid];
}

// ---------------------------------------------------------------------------
// Kernel 2: energies[b][s] = v[b] . enc[s][b][:]  -- EXACT round-2 config
// (2 s-rows per wave = best measured; 1-row and 4-row both slower).
// 32768 waves = 8192 blocks. Carries the 268 MB HBM read. Plain cached loads.
// ---------------------------------------------------------------------------
__global__ __launch_bounds__(256) void k_energies(const float* __restrict__ enc,
                                                  const float* __restrict__ v,
                                                  float* __restrict__ energies) {
    int wave = blockIdx.x * 4 + (threadIdx.x >> 6);  // 0..32767
    int lane = threadIdx.x & 63;
    int b  = wave & 31;                              // 0..31
    int sp = wave >> 5;                              // 0..1023 (s-pair)
    size_t s0 = (size_t)sp * 2;

    const float4* row0 = (const float4*)(enc + (s0 * BATCH + b) * SIZE);
    const float4* row1 = (const float4*)(enc + ((s0 + 1) * BATCH + b) * SIZE);
    const float4* vb   = (const float4*)(v + b * SIZE);

    float a0 = 0.f, a1 = 0.f;
    #pragma unroll
    for (int k = 0; k < 4; ++k) {
        int idx = lane + (k << 6);
        float4 e0 = row0[idx];
        float4 e1 = row1[idx];
        float4 vv = vb[idx];
        a0 += e0.x * vv.x + e0.y * vv.y + e0.z * vv.z + e0.w * vv.w;
        a1 += e1.x * vv.x + e1.y * vv.y + e1.z * vv.z + e1.w * vv.w;
    }
    #pragma unroll
    for (int off = 32; off; off >>= 1) {
        a0 += __shfl_down(a0, off, 64);
        a1 += __shfl_down(a1, off, 64);
    }
    if (lane == 0)
        ((float2*)(energies + b * SEQ))[sp] = make_float2(a0, a1);
}

// ---------------------------------------------------------------------------
// Kernel 3: row softmax over s. One block per b; 256 threads x 8 elems each.
// Bias term is constant over s and cancels under softmax shift invariance.
// ---------------------------------------------------------------------------
__global__ __launch_bounds__(256) void k_softmax(const float* __restrict__ energies,
                                                 float* __restrict__ out) {
    int b = blockIdx.x;
    const float* row = energies + b * SEQ;
    int t = threadIdx.x;
    int wid = t >> 6, lane = t & 63;

    float vals[8];
    float m = -INFINITY;
    #pragma unroll
    for (int i = 0; i < 8; ++i) {
        vals[i] = row[t + (i << 8)];
        m = fmaxf(m, vals[i]);
    }
    __shared__ float redm[4];
    #pragma unroll
    for (int off = 32; off; off >>= 1) m = fmaxf(m, __shfl_down(m, off, 64));
    if (lane == 0) redm[wid] = m;
    __syncthreads();
    m = fmaxf(fmaxf(redm[0], redm[1]), fmaxf(redm[2], redm[3]));

    float sum = 0.f;
    #pragma unroll
    for (int i = 0; i < 8; ++i) {
        vals[i] = __expf(vals[i] - m);
        sum += vals[i];
    }
    __shared__ float reds[4];
    #pragma unroll
    for (int off = 32; off; off >>= 1) sum += __shfl_down(sum, off, 64);
    if (lane == 0) reds[wid] = sum;
    __syncthreads();
    sum = reds[0] + reds[1] + reds[2] + reds[3];

    float inv = 1.f / sum;
    #pragma unroll
    for (int i = 0; i < 8; ++i)
        out[b * SEQ + t + (i << 8)] = vals[i] * inv;
}

// ---------------------------------------------------------------------------
extern "C" void kernel_launch(void* const* d_in, const int* in_sizes, int n_in,
                              void* d_out, int out_size, void* d_ws, size_t ws_size,
                              hipStream_t stream) {
    const float* dh  = (const float*)d_in[0];   // [32, 1024]
    const float* enc = (const float*)d_in[1];   // [2048, 32, 1024]
    const float* W   = (const float*)d_in[2];   // [1024, 1024]
    // d_in[3] = bias: unused (cancels under softmax shift invariance)

    float* ws       = (float*)d_ws;
    float* v        = ws;                                   // 32*1024 = 32768 f
    float* energies = v + BATCH * SIZE;                     // 32*2048 = 65536 f

    k_project <<<BATCH * 16, 256, 0, stream>>>(dh, W, v);
    k_energies<<<(BATCH * SEQ / 2) / 4, 256, 0, stream>>>(enc, v, energies);
    k_softmax <<<BATCH, 256, 0, stream>>>(energies, (float*)d_out);
}